// Round 5
// baseline (546.395 us; speedup 1.0000x reference)
//
#include <hip/hip_runtime.h>
#include <math.h>

#define C_DIM 96
#define CR 24
#define H_DIM 128
#define W_DIM 128
#define B_DIM 32
#define N_PLANES (B_DIM * C_DIM)     // 3072 pool tasks
#define N_CONV   (N_PLANES / 2)      // 1536 conv tasks (2 planes each)
#define GRID 2048
#define ROWS_PER_CHUNK 32

typedef float nfloat4 __attribute__((ext_vector_type(4)));

// ws layout: [0..63] int control block, [64..] pooled floats (3072)
//   ctrl[0] = pool task counter, ctrl[1] = conv task counter, ctrl[2+b] = batch_done[b]
// hipMemsetAsync zeroes the first 256 bytes each launch; pooled needs no init
// (guarded by batch_done).

__global__ void __launch_bounds__(256) fused_all_kernel(const float* __restrict__ x,
                                                        const float* __restrict__ w1,
                                                        const float* __restrict__ gamma,
                                                        const float* __restrict__ beta,
                                                        const float* __restrict__ rmean,
                                                        const float* __restrict__ rvar,
                                                        const float* __restrict__ w2,
                                                        const float* __restrict__ b2,
                                                        const float* __restrict__ bias,
                                                        float* __restrict__ out,
                                                        int* __restrict__ ctrl,
                                                        float* __restrict__ pooled) {
    int tid = threadIdx.x;
    __shared__ int task;
    __shared__ float red[4];

    // ---------------- Phase A: pool tasks (work-stealing, batch-ordered) ----------------
    for (;;) {
        if (tid == 0) task = atomicAdd(&ctrl[0], 1);
        __syncthreads();
        int t = task;
        __syncthreads();
        if (t >= N_PLANES) break;

        const float4* xp = (const float4*)(x + (size_t)t * (H_DIM * W_DIM));
        float s = 0.f;
        for (int i = tid; i < 4096; i += 256) {
            float4 v = xp[i];
            s += v.x + v.y + v.z + v.w;
        }
        for (int off = 32; off; off >>= 1) s += __shfl_down(s, off, 64);
        if ((tid & 63) == 0) red[tid >> 6] = s;
        __syncthreads();
        if (tid == 0) {
            float m = (red[0] + red[1] + red[2] + red[3]) * (1.f / (H_DIM * W_DIM));
            __hip_atomic_store(&pooled[t], m, __ATOMIC_RELAXED, __HIP_MEMORY_SCOPE_AGENT);
            __hip_atomic_fetch_add(&ctrl[2 + t / C_DIM], 1, __ATOMIC_RELEASE, __HIP_MEMORY_SCOPE_AGENT);
        }
        __syncthreads();   // red[] / task reuse
    }

    // ---------------- Phase B: conv tasks (spin until batch means ready) ----------------
    __shared__ float pl[C_DIM];
    __shared__ float h1[CR];
    __shared__ float wsm[2][10];

    for (;;) {
        if (tid == 0) task = atomicAdd(&ctrl[1], 1);
        __syncthreads();
        int t = task;
        __syncthreads();
        if (t >= N_CONV) return;

        int plane0 = t * 2;
        int b = plane0 / C_DIM;
        int c0 = plane0 % C_DIM;           // plane1 channel = c0+1 (never straddles batch: 96 even)

        if (tid == 0) {
            while (__hip_atomic_load(&ctrl[2 + b], __ATOMIC_ACQUIRE, __HIP_MEMORY_SCOPE_AGENT) < C_DIM)
                __builtin_amdgcn_s_sleep(8);
        }
        __syncthreads();

        if (tid < C_DIM)
            pl[tid] = __hip_atomic_load(&pooled[b * C_DIM + tid], __ATOMIC_RELAXED, __HIP_MEMORY_SCOPE_AGENT);
        __syncthreads();
        if (tid < CR) {
            float s = 0.f;
            const float* wr = w1 + tid * C_DIM;
            #pragma unroll 8
            for (int c = 0; c < C_DIM; c++) s += pl[c] * wr[c];
            s = (s - rmean[tid]) * rsqrtf(rvar[tid] + 1e-5f) * gamma[tid] + beta[tid];
            h1[tid] = 1.f / (1.f + expf(-s));
        }
        __syncthreads();
        if (tid < 20) {
            if (tid < 18) {
                int p = tid / 9, k = tid % 9;
                int row = (c0 + p) * 9 + k;
                float s = b2[row];
                const float* wr = w2 + row * CR;
                #pragma unroll
                for (int j = 0; j < CR; j++) s += h1[j] * wr[j];
                wsm[p][k] = s;
            } else {
                wsm[tid - 18][9] = bias[c0 + (tid - 18)];
            }
        }
        __syncthreads();

        // per-thread tile: g = col group (4 cols), chunk = 32-row band, p = plane select
        int g = tid & 31;
        int chunk = (tid >> 5) & 3;
        int p = tid >> 7;
        int plane = plane0 + p;
        int col = g << 2;
        int r0 = chunk * ROWS_PER_CHUNK;

        const float* xp = x + (size_t)plane * (H_DIM * W_DIM);
        float* op = out + (size_t)plane * (H_DIM * W_DIM);
        const float* wv = wsm[p];
        float w00 = wv[0], w01 = wv[1], w02 = wv[2];
        float w10 = wv[3], w11 = wv[4], w12 = wv[5];
        float w20 = wv[6], w21 = wv[7], w22 = wv[8];
        float bb = wv[9];
        const bool leftEdge = (g == 0), rightEdge = (g == 31);

        float4 pv, cv, nv;
        float plh, prh, clh, crh, nlh, nrh;

        {
            int r = r0 - 1;
            float4 v;
            if (r >= 0) v = *(const float4*)(xp + r * W_DIM + col);
            else { v.x = v.y = v.z = v.w = 0.f; }
            float l = __shfl_up(v.w, 1, 64);
            float rr = __shfl_down(v.x, 1, 64);
            pv = v; plh = leftEdge ? 0.f : l; prh = rightEdge ? 0.f : rr;
        }
        {
            float4 v = *(const float4*)(xp + r0 * W_DIM + col);
            float l = __shfl_up(v.w, 1, 64);
            float rr = __shfl_down(v.x, 1, 64);
            cv = v; clh = leftEdge ? 0.f : l; crh = rightEdge ? 0.f : rr;
        }

        #pragma unroll 4
        for (int i = 0; i < ROWS_PER_CHUNK; i++) {
            int r = r0 + i;
            float4 v;
            if (r + 1 < H_DIM) v = *(const float4*)(xp + (r + 1) * W_DIM + col);
            else { v.x = v.y = v.z = v.w = 0.f; }
            float l = __shfl_up(v.w, 1, 64);
            float rr = __shfl_down(v.x, 1, 64);
            nv = v; nlh = leftEdge ? 0.f : l; nrh = rightEdge ? 0.f : rr;

            nfloat4 o;
            o.x = w00 * plh  + w01 * pv.x + w02 * pv.y
                + w10 * clh  + w11 * cv.x + w12 * cv.y
                + w20 * nlh  + w21 * nv.x + w22 * nv.y + bb;
            o.y = w00 * pv.x + w01 * pv.y + w02 * pv.z
                + w10 * cv.x + w11 * cv.y + w12 * cv.z
                + w20 * nv.x + w21 * nv.y + w22 * nv.z + bb;
            o.z = w00 * pv.y + w01 * pv.z + w02 * pv.w
                + w10 * cv.y + w11 * cv.z + w12 * cv.w
                + w20 * nv.y + w21 * nv.z + w22 * nv.w + bb;
            o.w = w00 * pv.z + w01 * pv.w + w02 * prh
                + w10 * cv.z + w11 * cv.w + w12 * crh
                + w20 * nv.z + w21 * nv.w + w22 * nrh + bb;
            __builtin_nontemporal_store(o, (nfloat4*)(op + r * W_DIM + col));

            pv = cv; plh = clh; prh = crh;
            cv = nv; clh = nlh; crh = nrh;
        }
        __syncthreads();   // protect pl/h1/wsm/task before next task
    }
}

extern "C" void kernel_launch(void* const* d_in, const int* in_sizes, int n_in,
                              void* d_out, int out_size, void* d_ws, size_t ws_size,
                              hipStream_t stream) {
    const float* x     = (const float*)d_in[0];
    const float* w1    = (const float*)d_in[1];
    const float* gamma = (const float*)d_in[2];
    const float* beta  = (const float*)d_in[3];
    const float* rmean = (const float*)d_in[4];
    const float* rvar  = (const float*)d_in[5];
    const float* w2    = (const float*)d_in[6];
    const float* b2    = (const float*)d_in[7];
    const float* bias  = (const float*)d_in[8];
    float* out = (float*)d_out;

    int*   ctrl   = (int*)d_ws;                 // 64 ints reserved (256 B)
    float* pooled = (float*)((char*)d_ws + 256);

    hipMemsetAsync(d_ws, 0, 256, stream);       // zero task counters + batch_done
    fused_all_kernel<<<GRID, 256, 0, stream>>>(
        x, w1, gamma, beta, rmean, rvar, w2, b2, bias, out, ctrl, pooled);
}